// Round 5
// baseline (489.639 us; speedup 1.0000x reference)
//
#include <hip/hip_runtime.h>
#include <math.h>

constexpr int N = 50000;
constexpr int E = 800000;
constexpr int D = 32;     // layer dim
constexpr int R = 20;     // relations
constexpr int B = 4;      // bases
constexpr int EPB = 16;   // edges per block in edge kernel (512 thr / 32)
constexpr int REC = 160;  // ushorts per node record: 32 sA + 128 xb (320 B)

__device__ __forceinline__ unsigned short f2bf(float f) {
    unsigned u = __float_as_uint(f);
    u = (u + 0x7fffu + ((u >> 16) & 1u)) >> 16;   // round-to-nearest-even
    return (unsigned short)u;
}
__device__ __forceinline__ float bf2f(unsigned short h) {
    return __uint_as_float((unsigned)h << 16);
}

// ---------------------------------------------------------------------------
// attnA[l][r] = attn_tab[r] @ Aw[l][64:96] + Ab[l]    [2, R, D]
__global__ void prep_attnA(const float* __restrict__ attn_tab,
                           const float* __restrict__ Aw0,
                           const float* __restrict__ Ab0,
                           const float* __restrict__ Aw1,
                           const float* __restrict__ Ab1,
                           float* __restrict__ attnA) {
    int b = blockIdx.x;           // 0..2R-1
    int l = b / R, r = b % R;
    int j = threadIdx.x;          // 0..31
    const float* Aw = l ? Aw1 : Aw0;
    const float* Ab = l ? Ab1 : Ab0;
    float acc = Ab[j];
    for (int k = 0; k < 32; ++k)
        acc = fmaf(attn_tab[r * 32 + k], Aw[(64 + k) * D + j], acc);
    attnA[((size_t)l * R + r) * D + j] = acc;
}

// ---------------------------------------------------------------------------
// Counting sort of edges by dst.
__global__ void zero_cnt(int* __restrict__ cnt) {
    int i = blockIdx.x * blockDim.x + threadIdx.x;
    if (i < N) cnt[i] = 0;
}

__global__ void hist_dst(const int* __restrict__ dst, int* __restrict__ cnt) {
    int e = blockIdx.x * blockDim.x + threadIdx.x;
    if (e < E) atomicAdd(&cnt[dst[e]], 1);
}

constexpr int SCB = 1024;
constexpr int NSCB = (N + SCB - 1) / SCB;   // 49

__global__ __launch_bounds__(SCB)
void scan_block_sums(const int* __restrict__ cnt, int* __restrict__ bsum) {
    __shared__ int sdata[SCB];
    int i = blockIdx.x * SCB + threadIdx.x;
    sdata[threadIdx.x] = (i < N) ? cnt[i] : 0;
    __syncthreads();
    for (int s = SCB / 2; s > 0; s >>= 1) {
        if (threadIdx.x < s) sdata[threadIdx.x] += sdata[threadIdx.x + s];
        __syncthreads();
    }
    if (threadIdx.x == 0) bsum[blockIdx.x] = sdata[0];
}

__global__ void scan_bsum(int* __restrict__ bsum) {
    int t = threadIdx.x;  // 64 threads, one wave
    int orig = (t < NSCB) ? bsum[t] : 0;
    int v = orig;
#pragma unroll
    for (int d = 1; d < 64; d <<= 1) {
        int u = __shfl_up(v, d, 64);
        if (t >= d) v += u;
    }
    if (t < NSCB) bsum[t] = v - orig;  // exclusive prefix of block sums
}

__global__ __launch_bounds__(SCB)
void scan_final(const int* __restrict__ cnt, const int* __restrict__ bsum,
                int* __restrict__ off, int* __restrict__ cur) {
    __shared__ int sdata[SCB];
    int i = blockIdx.x * SCB + threadIdx.x;
    int v = (i < N) ? cnt[i] : 0;
    sdata[threadIdx.x] = v;
    __syncthreads();
    for (int d = 1; d < SCB; d <<= 1) {
        int u = (threadIdx.x >= (unsigned)d) ? sdata[threadIdx.x - d] : 0;
        __syncthreads();
        sdata[threadIdx.x] += u;
        __syncthreads();
    }
    if (i < N) {
        int excl = sdata[threadIdx.x] - v + bsum[blockIdx.x];
        off[i] = excl;
        cur[i] = excl;
        if (i == N - 1) off[N] = excl + v;   // == E
    }
}

// es[k] = {src | ety<<16, dst} in dst-sorted order (src,dst < 2^16, ety < 32)
__global__ void scatter_edges(const int* __restrict__ src,
                              const int* __restrict__ dst,
                              const int* __restrict__ ety,
                              int* __restrict__ cur,
                              int2* __restrict__ es) {
    int e = blockIdx.x * blockDim.x + threadIdx.x;
    if (e >= E) return;
    int d = dst[e];
    int pos = atomicAdd(&cur[d], 1);
    es[pos] = make_int2(src[e] | (ety[e] << 16), d);
}

// ---------------------------------------------------------------------------
// Node stage layer 0 (fused x0 build), 32 lanes per node:
//   x = concat(feat, embed[idx]) computed in-reg
//   rec[n] = {bf16 sA (x@Aw[0:32]), bf16 xb[j][b] (x@bases)}
//   dA[n]  = x@Aw[32:64]   (fp32)
//   nei[n] = x@selfw       (self-loop term as the accumulator init)
__global__ void node_stage_l0(const float* __restrict__ feat,
                              const float* __restrict__ embed,
                              const int* __restrict__ idx,
                              const float* __restrict__ Aw,
                              const float* __restrict__ bases,
                              const float* __restrict__ selfw,
                              unsigned short* __restrict__ rec,
                              float* __restrict__ dA,
                              float* __restrict__ nei) {
    int t = blockIdx.x * blockDim.x + threadIdx.x;
    int n = t >> 5, j = t & 31;
    if (n >= N) return;
    float xv = (j < 16) ? feat[n * 16 + j] : embed[idx[n] * 16 + (j - 16)];
    float sa = 0.f, da = 0.f, cu = 0.f;
    float b0 = 0.f, b1 = 0.f, b2 = 0.f, b3 = 0.f;
#pragma unroll
    for (int i = 0; i < D; ++i) {
        float xi = __shfl(xv, i, 32);
        sa = fmaf(xi, Aw[i * D + j], sa);
        da = fmaf(xi, Aw[(D + i) * D + j], da);
        b0 = fmaf(xi, bases[0 * D * D + i * D + j], b0);
        b1 = fmaf(xi, bases[1 * D * D + i * D + j], b1);
        b2 = fmaf(xi, bases[2 * D * D + i * D + j], b2);
        b3 = fmaf(xi, bases[3 * D * D + i * D + j], b3);
        cu = fmaf(xi, selfw[i * D + j], cu);
    }
    unsigned short* rn = rec + (size_t)n * REC;
    rn[j] = f2bf(sa);
    *(ushort4*)(rn + 32 + j * 4) =
        make_ushort4(f2bf(b0), f2bf(b1), f2bf(b2), f2bf(b3));
    dA[n * D + j] = da;
    nei[n * D + j] = cu;
}

// ---------------------------------------------------------------------------
// Node stage layer 1: x1 = relu(nei) (fused layer-0 finalize), then same as l0.
// nei is read then overwritten with the new self-loop term (own element: safe).
__global__ void node_stage_l1(const float* __restrict__ Aw,
                              const float* __restrict__ bases,
                              const float* __restrict__ selfw,
                              unsigned short* __restrict__ rec,
                              float* __restrict__ dA,
                              float* __restrict__ nei) {
    int t = blockIdx.x * blockDim.x + threadIdx.x;
    int n = t >> 5, j = t & 31;
    if (n >= N) return;
    float xv = fmaxf(nei[n * D + j], 0.f);
    float sa = 0.f, da = 0.f, cu = 0.f;
    float b0 = 0.f, b1 = 0.f, b2 = 0.f, b3 = 0.f;
#pragma unroll
    for (int i = 0; i < D; ++i) {
        float xi = __shfl(xv, i, 32);
        sa = fmaf(xi, Aw[i * D + j], sa);
        da = fmaf(xi, Aw[(D + i) * D + j], da);
        b0 = fmaf(xi, bases[0 * D * D + i * D + j], b0);
        b1 = fmaf(xi, bases[1 * D * D + i * D + j], b1);
        b2 = fmaf(xi, bases[2 * D * D + i * D + j], b2);
        b3 = fmaf(xi, bases[3 * D * D + i * D + j], b3);
        cu = fmaf(xi, selfw[i * D + j], cu);
    }
    unsigned short* rn = rec + (size_t)n * REC;
    rn[j] = f2bf(sa);
    *(ushort4*)(rn + 32 + j * 4) =
        make_ushort4(f2bf(b0), f2bf(b1), f2bf(b2), f2bf(b3));
    dA[n * D + j] = da;
    nei[n * D + j] = cu;
}

// ---------------------------------------------------------------------------
// Edge stage over dst-sorted edges: 16 edges/block, 32 lanes/edge.
//   gather: rec[src] (bf16, 2 loads/lane) + dA[dst] (seq) + attnA[r]
//   msg_j = sum_b wcomp[r,b] * xb[s,j,b]            (4 fma)
//   a     = sigmoid(dot(relu(sA[s]+dA[d]+attnA[r]), Bw) + Bb)
//   LDS segmented reduction over equal-dst runs -> 1 atomic per run.
__global__ __launch_bounds__(512)
void edge_stage(const unsigned short* __restrict__ rec,
                const float* __restrict__ dA,
                const float* __restrict__ attnA,
                const float* __restrict__ wcomp,
                const float* __restrict__ Bw,
                const float* __restrict__ Bb,
                const int2* __restrict__ es,
                float* __restrict__ nei) {
    __shared__ float accs[EPB][32];
    __shared__ int ed[EPB];
    int t = blockIdx.x * blockDim.x + threadIdx.x;
    int k = t >> 5;                 // sorted edge index
    int j = t & 31;
    int g = threadIdx.x >> 5;       // group within block

    int d = -1 - g;                 // unique invalid marker per group
    float val = 0.f;
    if (k < E) {
        int2 e = es[k];
        int s = e.x & 0xffff;
        int r = ((unsigned)e.x) >> 16;
        d = e.y;
        const unsigned short* rn = rec + (size_t)s * REC;
        // attention score
        float h = bf2f(rn[j]) + dA[d * D + j] + attnA[r * D + j];
        h = fmaxf(h, 0.f);
        float p = h * Bw[j];
#pragma unroll
        for (int o = 16; o > 0; o >>= 1)
            p += __shfl_xor(p, o, 32);
        float a = 1.f / (1.f + __expf(-(p + Bb[0])));
        // message: 4 fma via basis factorization (bf16 xb)
        const float4 wc = *(const float4*)(wcomp + r * B);
        ushort4 xv = *(const ushort4*)(rn + 32 + j * 4);
        float m = wc.x * bf2f(xv.x);
        m = fmaf(wc.y, bf2f(xv.y), m);
        m = fmaf(wc.z, bf2f(xv.z), m);
        m = fmaf(wc.w, bf2f(xv.w), m);
        val = a * m;
    }
    accs[g][j] = val;
    if (j == 0) ed[g] = d;
    __syncthreads();

    // run leaders flush their run with one atomic per column
    bool lead = (g == 0) || (ed[g - 1] != d);
    if (lead && d >= 0) {
        float sum = accs[g][j];
        for (int g2 = g + 1; g2 < EPB; ++g2) {
            if (ed[g2] != d) break;
            sum += accs[g2][j];
        }
        atomicAdd(&nei[(size_t)d * D + j], sum);
    }
}

// ---------------------------------------------------------------------------
// out = relu(nei)  (vectorized elementwise)
__global__ void finalize(const float4* __restrict__ nei, float4* __restrict__ out) {
    int t = blockIdx.x * blockDim.x + threadIdx.x;
    if (t >= N * D / 4) return;
    float4 v = nei[t];
    v.x = fmaxf(v.x, 0.f); v.y = fmaxf(v.y, 0.f);
    v.z = fmaxf(v.z, 0.f); v.w = fmaxf(v.w, 0.f);
    out[t] = v;
}

// ---------------------------------------------------------------------------
extern "C" void kernel_launch(void* const* d_in, const int* in_sizes, int n_in,
                              void* d_out, int out_size, void* d_ws, size_t ws_size,
                              hipStream_t stream) {
    const float* feat  = (const float*)d_in[0];
    const float* embed = (const float*)d_in[1];
    const float* attn  = (const float*)d_in[2];
    const int*   idx   = (const int*)d_in[3];
    const int*   src   = (const int*)d_in[4];
    const int*   dst   = (const int*)d_in[5];
    const int*   ety   = (const int*)d_in[6];
    const float* bases[2] = {(const float*)d_in[7],  (const float*)d_in[14]};
    const float* wcomp[2] = {(const float*)d_in[8],  (const float*)d_in[15]};
    const float* selfw[2] = {(const float*)d_in[9],  (const float*)d_in[16]};
    const float* Aw[2]    = {(const float*)d_in[10], (const float*)d_in[17]};
    const float* Ab[2]    = {(const float*)d_in[11], (const float*)d_in[18]};
    const float* Bw[2]    = {(const float*)d_in[12], (const float*)d_in[19]};
    const float* Bb[2]    = {(const float*)d_in[13], (const float*)d_in[20]};
    float* out = (float*)d_out;

    // --- workspace layout ---
    // rec first (16B aligned at base), then fp32 arrays, then int arrays.
    char* wsb = (char*)d_ws;
    unsigned short* rec = (unsigned short*)wsb;           // N*REC ushorts = 16 MB
    size_t o = ((size_t)N * REC * sizeof(unsigned short) + 15) & ~(size_t)15;
    float* dA    = (float*)(wsb + o); o += (size_t)N * D * 4;        // 6.4 MB
    float* nei   = (float*)(wsb + o); o += (size_t)N * D * 4;        // 6.4 MB
    float* attnA = (float*)(wsb + o); o += (size_t)2 * R * D * 4;
    o = (o + 7) & ~(size_t)7;
    int2* es     = (int2*)(wsb + o); o += (size_t)E * 8;             // 6.4 MB
    int* cnt     = (int*)(wsb + o);  o += (size_t)N * 4;
    int* off     = (int*)(wsb + o);  o += (size_t)(N + 2) * 4;
    int* cur     = (int*)(wsb + o);  o += (size_t)N * 4;
    int* bsum    = (int*)(wsb + o);  o += (size_t)(NSCB + 1) * 4;

    dim3 blk(256);
    int gx = (N * D + 255) / 256;     // 6250: 32 lanes/node
    int ge = (E + 255) / 256;         // 3125: 1 thread/edge
    int gn = (N + 255) / 256;         // 196
    int gE = (E + EPB - 1) / EPB;     // 50000: 16 edges/block, 512 thr
    int gf = (N * D / 4 + 255) / 256;

    // one-time graph sort + tiny precompute
    zero_cnt<<<gn, blk, 0, stream>>>(cnt);
    prep_attnA<<<2 * R, 32, 0, stream>>>(attn, Aw[0], Ab[0], Aw[1], Ab[1], attnA);
    hist_dst<<<ge, blk, 0, stream>>>(dst, cnt);
    scan_block_sums<<<NSCB, SCB, 0, stream>>>(cnt, bsum);
    scan_bsum<<<1, 64, 0, stream>>>(bsum);
    scan_final<<<NSCB, SCB, 0, stream>>>(cnt, bsum, off, cur);
    scatter_edges<<<ge, blk, 0, stream>>>(src, dst, ety, cur, es);

    // layer 0
    node_stage_l0<<<gx, blk, 0, stream>>>(feat, embed, idx, Aw[0], bases[0],
                                          selfw[0], rec, dA, nei);
    edge_stage<<<gE, 512, 0, stream>>>(rec, dA, attnA, wcomp[0], Bw[0], Bb[0],
                                       es, nei);
    // layer 1 (fused relu of layer-0 output)
    node_stage_l1<<<gx, blk, 0, stream>>>(Aw[1], bases[1], selfw[1], rec, dA, nei);
    edge_stage<<<gE, 512, 0, stream>>>(rec, dA, attnA + (size_t)R * D,
                                       wcomp[1], Bw[1], Bb[1], es, nei);
    finalize<<<gf, blk, 0, stream>>>((const float4*)nei, (float4*)out);
}

// Round 6
// 439.004 us; speedup vs baseline: 1.1153x; 1.1153x over previous
//
#include <hip/hip_runtime.h>
#include <math.h>

constexpr int N = 50000;
constexpr int E = 800000;
constexpr int D = 32;     // layer dim
constexpr int R = 20;     // relations
constexpr int B = 4;      // bases
constexpr int EPB = 16;   // edges per block in edge kernel (512 thr / 32)
constexpr int RECW = 96;  // uints per node record: 32 lanes x 3 dwords (384 B)

__device__ __forceinline__ unsigned f2bf(float f) {
    unsigned u = __float_as_uint(f);
    u = (u + 0x7fffu + ((u >> 16) & 1u)) >> 16;   // round-to-nearest-even
    return u;
}

// ---------------------------------------------------------------------------
// attnA[l][r] = attn_tab[r] @ Aw[l][64:96] + Ab[l]    [2, R, D]
__global__ void prep_attnA(const float* __restrict__ attn_tab,
                           const float* __restrict__ Aw0,
                           const float* __restrict__ Ab0,
                           const float* __restrict__ Aw1,
                           const float* __restrict__ Ab1,
                           float* __restrict__ attnA) {
    int b = blockIdx.x;           // 0..2R-1
    int l = b / R, r = b % R;
    int j = threadIdx.x;          // 0..31
    const float* Aw = l ? Aw1 : Aw0;
    const float* Ab = l ? Ab1 : Ab0;
    float acc = Ab[j];
    for (int k = 0; k < 32; ++k)
        acc = fmaf(attn_tab[r * 32 + k], Aw[(64 + k) * D + j], acc);
    attnA[((size_t)l * R + r) * D + j] = acc;
}

// ---------------------------------------------------------------------------
// hist + rank: rank[e] = arrival order of e within its dst bucket
__global__ void hist_rank(const int* __restrict__ dst,
                          int* __restrict__ cnt,
                          int* __restrict__ rank) {
    int e = blockIdx.x * blockDim.x + threadIdx.x;
    if (e < E) rank[e] = atomicAdd(&cnt[dst[e]], 1);
}

// --- hierarchical exclusive scan of cnt[N] -> off[N+1] ---------------------
constexpr int SCB = 1024;
constexpr int NSCB = (N + SCB - 1) / SCB;   // 49

__global__ __launch_bounds__(SCB)
void scan_block_sums(const int* __restrict__ cnt, int* __restrict__ bsum) {
    __shared__ int sdata[SCB];
    int i = blockIdx.x * SCB + threadIdx.x;
    sdata[threadIdx.x] = (i < N) ? cnt[i] : 0;
    __syncthreads();
    for (int s = SCB / 2; s > 0; s >>= 1) {
        if (threadIdx.x < s) sdata[threadIdx.x] += sdata[threadIdx.x + s];
        __syncthreads();
    }
    if (threadIdx.x == 0) bsum[blockIdx.x] = sdata[0];
}

__global__ __launch_bounds__(SCB)
void scan_final(const int* __restrict__ cnt, const int* __restrict__ bsum,
                int* __restrict__ off) {
    __shared__ int sdata[SCB];
    __shared__ int bbase;
    // wave 0: sum of bsum[b] for b < blockIdx.x
    if (threadIdx.x < 64) {
        int v = (threadIdx.x < NSCB && (int)threadIdx.x < blockIdx.x)
                    ? bsum[threadIdx.x] : 0;
#pragma unroll
        for (int o = 32; o > 0; o >>= 1) v += __shfl_down(v, o, 64);
        if (threadIdx.x == 0) bbase = v;
    }
    int i = blockIdx.x * SCB + threadIdx.x;
    int v = (i < N) ? cnt[i] : 0;
    sdata[threadIdx.x] = v;
    __syncthreads();
    for (int d = 1; d < SCB; d <<= 1) {
        int u = (threadIdx.x >= (unsigned)d) ? sdata[threadIdx.x - d] : 0;
        __syncthreads();
        sdata[threadIdx.x] += u;
        __syncthreads();
    }
    if (i < N) {
        int excl = sdata[threadIdx.x] - v + bbase;
        off[i] = excl;
        if (i == N - 1) off[N] = excl + v;   // == E
    }
}

// es[pos] = {src | ety<<16, dst} in dst-sorted order (no atomics)
__global__ void scatter_edges(const int* __restrict__ src,
                              const int* __restrict__ dst,
                              const int* __restrict__ ety,
                              const int* __restrict__ off,
                              const int* __restrict__ rank,
                              int2* __restrict__ es) {
    int e = blockIdx.x * blockDim.x + threadIdx.x;
    if (e >= E) return;
    int d = dst[e];
    int pos = off[d] + rank[e];
    es[pos] = make_int2(src[e] | (ety[e] << 16), d);
}

// ---------------------------------------------------------------------------
// Node stage layer 0 (fused x0 build), 32 lanes per node:
//   rec lane-major: lane j -> {sA|xb0<<16, xb1|xb2<<16, xb3} (uint3, 12 B)
//   dA[n]  = x@Aw[32:64]   (fp32)
//   nei[n] = x@selfw       (self-loop term as the accumulator init)
__global__ void node_stage_l0(const float* __restrict__ feat,
                              const float* __restrict__ embed,
                              const int* __restrict__ idx,
                              const float* __restrict__ Aw,
                              const float* __restrict__ bases,
                              const float* __restrict__ selfw,
                              unsigned* __restrict__ rec,
                              float* __restrict__ dA,
                              float* __restrict__ nei) {
    int t = blockIdx.x * blockDim.x + threadIdx.x;
    int n = t >> 5, j = t & 31;
    if (n >= N) return;
    float xv = (j < 16) ? feat[n * 16 + j] : embed[idx[n] * 16 + (j - 16)];
    float sa = 0.f, da = 0.f, cu = 0.f;
    float b0 = 0.f, b1 = 0.f, b2 = 0.f, b3 = 0.f;
#pragma unroll
    for (int i = 0; i < D; ++i) {
        float xi = __shfl(xv, i, 32);
        sa = fmaf(xi, Aw[i * D + j], sa);
        da = fmaf(xi, Aw[(D + i) * D + j], da);
        b0 = fmaf(xi, bases[0 * D * D + i * D + j], b0);
        b1 = fmaf(xi, bases[1 * D * D + i * D + j], b1);
        b2 = fmaf(xi, bases[2 * D * D + i * D + j], b2);
        b3 = fmaf(xi, bases[3 * D * D + i * D + j], b3);
        cu = fmaf(xi, selfw[i * D + j], cu);
    }
    uint3 u;
    u.x = f2bf(sa) | (f2bf(b0) << 16);
    u.y = f2bf(b1) | (f2bf(b2) << 16);
    u.z = f2bf(b3);
    *(uint3*)(rec + (size_t)n * RECW + j * 3) = u;
    dA[n * D + j] = da;
    nei[n * D + j] = cu;
}

// ---------------------------------------------------------------------------
// Node stage layer 1: x1 = relu(nei) (fused layer-0 finalize), then same as l0.
__global__ void node_stage_l1(const float* __restrict__ Aw,
                              const float* __restrict__ bases,
                              const float* __restrict__ selfw,
                              unsigned* __restrict__ rec,
                              float* __restrict__ dA,
                              float* __restrict__ nei) {
    int t = blockIdx.x * blockDim.x + threadIdx.x;
    int n = t >> 5, j = t & 31;
    if (n >= N) return;
    float xv = fmaxf(nei[n * D + j], 0.f);
    float sa = 0.f, da = 0.f, cu = 0.f;
    float b0 = 0.f, b1 = 0.f, b2 = 0.f, b3 = 0.f;
#pragma unroll
    for (int i = 0; i < D; ++i) {
        float xi = __shfl(xv, i, 32);
        sa = fmaf(xi, Aw[i * D + j], sa);
        da = fmaf(xi, Aw[(D + i) * D + j], da);
        b0 = fmaf(xi, bases[0 * D * D + i * D + j], b0);
        b1 = fmaf(xi, bases[1 * D * D + i * D + j], b1);
        b2 = fmaf(xi, bases[2 * D * D + i * D + j], b2);
        b3 = fmaf(xi, bases[3 * D * D + i * D + j], b3);
        cu = fmaf(xi, selfw[i * D + j], cu);
    }
    uint3 u;
    u.x = f2bf(sa) | (f2bf(b0) << 16);
    u.y = f2bf(b1) | (f2bf(b2) << 16);
    u.z = f2bf(b3);
    *(uint3*)(rec + (size_t)n * RECW + j * 3) = u;
    dA[n * D + j] = da;
    nei[n * D + j] = cu;
}

// ---------------------------------------------------------------------------
// Edge stage over dst-sorted edges: 16 edges/block, 32 lanes/edge.
// One 12B load per lane supplies sA + all 4 xb values (bf16 in dword bits).
__global__ __launch_bounds__(512)
void edge_stage(const unsigned* __restrict__ rec,
                const float* __restrict__ dA,
                const float* __restrict__ attnA,
                const float* __restrict__ wcomp,
                const float* __restrict__ Bw,
                const float* __restrict__ Bb,
                const int2* __restrict__ es,
                float* __restrict__ nei) {
    __shared__ float accs[EPB][32];
    __shared__ int ed[EPB];
    int t = blockIdx.x * blockDim.x + threadIdx.x;
    int k = t >> 5;                 // sorted edge index
    int j = t & 31;
    int g = threadIdx.x >> 5;       // group within block

    int d = -1 - g;                 // unique invalid marker per group
    float val = 0.f;
    if (k < E) {
        int2 e = es[k];
        int s = e.x & 0xffff;
        int r = ((unsigned)e.x) >> 16;
        d = e.y;
        uint3 u = *(const uint3*)(rec + (size_t)s * RECW + j * 3);
        float sa = __uint_as_float(u.x << 16);
        float x0 = __uint_as_float(u.x & 0xffff0000u);
        float x1 = __uint_as_float(u.y << 16);
        float x2 = __uint_as_float(u.y & 0xffff0000u);
        float x3 = __uint_as_float(u.z << 16);
        // attention score
        float h = sa + dA[d * D + j] + attnA[r * D + j];
        h = fmaxf(h, 0.f);
        float p = h * Bw[j];
#pragma unroll
        for (int o = 16; o > 0; o >>= 1)
            p += __shfl_xor(p, o, 32);
        float a = 1.f / (1.f + __expf(-(p + Bb[0])));
        // message: 4 fma via basis factorization
        const float4 wc = *(const float4*)(wcomp + r * B);
        float m = wc.x * x0;
        m = fmaf(wc.y, x1, m);
        m = fmaf(wc.z, x2, m);
        m = fmaf(wc.w, x3, m);
        val = a * m;
    }
    accs[g][j] = val;
    if (j == 0) ed[g] = d;
    __syncthreads();

    // run leaders flush their run with one atomic per column
    bool lead = (g == 0) || (ed[g - 1] != d);
    if (lead && d >= 0) {
        float sum = accs[g][j];
        for (int g2 = g + 1; g2 < EPB; ++g2) {
            if (ed[g2] != d) break;
            sum += accs[g2][j];
        }
        atomicAdd(&nei[(size_t)d * D + j], sum);
    }
}

// ---------------------------------------------------------------------------
// out = relu(nei)  (vectorized elementwise)
__global__ void finalize(const float4* __restrict__ nei, float4* __restrict__ out) {
    int t = blockIdx.x * blockDim.x + threadIdx.x;
    if (t >= N * D / 4) return;
    float4 v = nei[t];
    v.x = fmaxf(v.x, 0.f); v.y = fmaxf(v.y, 0.f);
    v.z = fmaxf(v.z, 0.f); v.w = fmaxf(v.w, 0.f);
    out[t] = v;
}

// ---------------------------------------------------------------------------
extern "C" void kernel_launch(void* const* d_in, const int* in_sizes, int n_in,
                              void* d_out, int out_size, void* d_ws, size_t ws_size,
                              hipStream_t stream) {
    const float* feat  = (const float*)d_in[0];
    const float* embed = (const float*)d_in[1];
    const float* attn  = (const float*)d_in[2];
    const int*   idx   = (const int*)d_in[3];
    const int*   src   = (const int*)d_in[4];
    const int*   dst   = (const int*)d_in[5];
    const int*   ety   = (const int*)d_in[6];
    const float* bases[2] = {(const float*)d_in[7],  (const float*)d_in[14]};
    const float* wcomp[2] = {(const float*)d_in[8],  (const float*)d_in[15]};
    const float* selfw[2] = {(const float*)d_in[9],  (const float*)d_in[16]};
    const float* Aw[2]    = {(const float*)d_in[10], (const float*)d_in[17]};
    const float* Ab[2]    = {(const float*)d_in[11], (const float*)d_in[18]};
    const float* Bw[2]    = {(const float*)d_in[12], (const float*)d_in[19]};
    const float* Bb[2]    = {(const float*)d_in[13], (const float*)d_in[20]};
    float* out = (float*)d_out;

    // --- workspace layout ---
    char* wsb = (char*)d_ws;
    unsigned* rec = (unsigned*)wsb;                       // N*RECW uints = 19.2 MB
    size_t o = ((size_t)N * RECW * 4 + 15) & ~(size_t)15;
    float* dA    = (float*)(wsb + o); o += (size_t)N * D * 4;        // 6.4 MB
    float* nei   = (float*)(wsb + o); o += (size_t)N * D * 4;        // 6.4 MB
    float* attnA = (float*)(wsb + o); o += (size_t)2 * R * D * 4;
    o = (o + 7) & ~(size_t)7;
    int2* es     = (int2*)(wsb + o); o += (size_t)E * 8;             // 6.4 MB
    int* cnt     = (int*)(wsb + o);  o += (size_t)N * 4;
    int* off     = (int*)(wsb + o);  o += (size_t)(N + 2) * 4;
    int* rank    = (int*)(wsb + o);  o += (size_t)E * 4;             // 3.2 MB
    int* bsum    = (int*)(wsb + o);  o += (size_t)(NSCB + 1) * 4;

    dim3 blk(256);
    int gx = (N * D + 255) / 256;     // 6250: 32 lanes/node
    int ge = (E + 255) / 256;         // 3125: 1 thread/edge
    int gE = (E + EPB - 1) / EPB;     // 50000: 16 edges/block, 512 thr
    int gf = (N * D / 4 + 255) / 256;

    // one-time graph sort + tiny precompute
    hipMemsetAsync(cnt, 0, (size_t)N * 4, stream);
    prep_attnA<<<2 * R, 32, 0, stream>>>(attn, Aw[0], Ab[0], Aw[1], Ab[1], attnA);
    hist_rank<<<ge, blk, 0, stream>>>(dst, cnt, rank);
    scan_block_sums<<<NSCB, SCB, 0, stream>>>(cnt, bsum);
    scan_final<<<NSCB, SCB, 0, stream>>>(cnt, bsum, off);
    scatter_edges<<<ge, blk, 0, stream>>>(src, dst, ety, off, rank, es);

    // layer 0
    node_stage_l0<<<gx, blk, 0, stream>>>(feat, embed, idx, Aw[0], bases[0],
                                          selfw[0], rec, dA, nei);
    edge_stage<<<gE, 512, 0, stream>>>(rec, dA, attnA, wcomp[0], Bw[0], Bb[0],
                                       es, nei);
    // layer 1 (fused relu of layer-0 output)
    node_stage_l1<<<gx, blk, 0, stream>>>(Aw[1], bases[1], selfw[1], rec, dA, nei);
    edge_stage<<<gE, 512, 0, stream>>>(rec, dA, attnA + (size_t)R * D,
                                       wcomp[1], Bw[1], Bb[1], es, nei);
    finalize<<<gf, blk, 0, stream>>>((const float4*)nei, (float4*)out);
}

// Round 8
// 353.240 us; speedup vs baseline: 1.3861x; 1.2428x over previous
//
#include <hip/hip_runtime.h>
#include <math.h>

constexpr int N = 50000;
constexpr int E = 800000;
constexpr int D = 32;      // layer dim
constexpr int R = 20;      // relations
constexpr int RECW = 96;   // uints per node record: 32 lanes x 3 dwords (384 B)

// edge kernel geometry
constexpr int EG = 2048;                   // blocks
constexpr int ET = 256;                    // threads/block
constexpr int ENG = EG * (ET / 32);        // 16384 32-lane groups
constexpr int ECE = (E + ENG - 1) / ENG;   // 49 sorted edges per group

__device__ __forceinline__ unsigned f2bf(float f) {
    unsigned u = __float_as_uint(f);
    return (u + 0x7fffu + ((u >> 16) & 1u)) >> 16;   // RNE to bf16 bits
}

// ---------------------------------------------------------------------------
// hist+rank over edges; trailing blocks compute attnA[2][R][32].
constexpr int GEH = (E + 255) / 256;   // 3125
__global__ void hist_rank_attnA(const int* __restrict__ dst,
                                int* __restrict__ cnt,
                                int* __restrict__ rank,
                                const float* __restrict__ attn,
                                const float* __restrict__ Aw0,
                                const float* __restrict__ Ab0,
                                const float* __restrict__ Aw1,
                                const float* __restrict__ Ab1,
                                float* __restrict__ attnA) {
    int b = blockIdx.x;
    if (b < GEH) {
        int e = b * 256 + threadIdx.x;
        if (e < E) rank[e] = atomicAdd(&cnt[dst[e]], 1);
    } else {
        int i = (b - GEH) * 256 + threadIdx.x;   // 0..1279
        if (i < 2 * R * 32) {
            int l = i / (R * 32), rem = i % (R * 32), r = rem / 32, jj = rem & 31;
            const float* Aw = l ? Aw1 : Aw0;
            const float* Ab = l ? Ab1 : Ab0;
            float acc = Ab[jj];
            for (int k = 0; k < 32; ++k)
                acc = fmaf(attn[r * 32 + k], Aw[(64 + k) * D + jj], acc);
            attnA[i] = acc;
        }
    }
}

// --- hierarchical exclusive scan of cnt[N] -> off[N+1] ---------------------
constexpr int SCB = 1024;
constexpr int NSCB = (N + SCB - 1) / SCB;   // 49

__global__ __launch_bounds__(SCB)
void scan_block_sums(const int* __restrict__ cnt, int* __restrict__ bsum) {
    __shared__ int sdata[SCB];
    int i = blockIdx.x * SCB + threadIdx.x;
    sdata[threadIdx.x] = (i < N) ? cnt[i] : 0;
    __syncthreads();
    for (int s = SCB / 2; s > 0; s >>= 1) {
        if (threadIdx.x < s) sdata[threadIdx.x] += sdata[threadIdx.x + s];
        __syncthreads();
    }
    if (threadIdx.x == 0) bsum[blockIdx.x] = sdata[0];
}

__global__ __launch_bounds__(SCB)
void scan_final(const int* __restrict__ cnt, const int* __restrict__ bsum,
                int* __restrict__ off) {
    __shared__ int sdata[SCB];
    __shared__ int bbase;
    if (threadIdx.x < 64) {
        int v = (threadIdx.x < NSCB && (int)threadIdx.x < blockIdx.x)
                    ? bsum[threadIdx.x] : 0;
#pragma unroll
        for (int o = 32; o > 0; o >>= 1) v += __shfl_down(v, o, 64);
        if (threadIdx.x == 0) bbase = v;
    }
    int i = blockIdx.x * SCB + threadIdx.x;
    int v = (i < N) ? cnt[i] : 0;
    sdata[threadIdx.x] = v;
    __syncthreads();
    for (int d = 1; d < SCB; d <<= 1) {
        int u = (threadIdx.x >= (unsigned)d) ? sdata[threadIdx.x - d] : 0;
        __syncthreads();
        sdata[threadIdx.x] += u;
        __syncthreads();
    }
    if (i < N) {
        int excl = sdata[threadIdx.x] - v + bbase;
        off[i] = excl;
        if (i == N - 1) off[N] = excl + v;   // == E
    }
}

// es[pos] = {src | ety<<16, dst} in dst-sorted order (no atomics)
__global__ void scatter_edges(const int* __restrict__ src,
                              const int* __restrict__ dst,
                              const int* __restrict__ ety,
                              const int* __restrict__ off,
                              const int* __restrict__ rank,
                              int2* __restrict__ es) {
    int e = blockIdx.x * blockDim.x + threadIdx.x;
    if (e >= E) return;
    int d = dst[e];
    es[off[d] + rank[e]] = make_int2(src[e] | (ety[e] << 16), d);
}

// ---------------------------------------------------------------------------
// Node stage layer 0 (fused x0 build), 32 lanes per node.
__global__ void node_stage_l0(const float* __restrict__ feat,
                              const float* __restrict__ embed,
                              const int* __restrict__ idx,
                              const float* __restrict__ Aw,
                              const float* __restrict__ bases,
                              const float* __restrict__ selfw,
                              unsigned* __restrict__ rec,
                              float* __restrict__ dA,
                              float* __restrict__ nei) {
    int t = blockIdx.x * blockDim.x + threadIdx.x;
    int n = t >> 5, j = t & 31;
    if (n >= N) return;
    float xv = (j < 16) ? feat[n * 16 + j] : embed[idx[n] * 16 + (j - 16)];
    float sa = 0.f, da = 0.f, cu = 0.f;
    float b0 = 0.f, b1 = 0.f, b2 = 0.f, b3 = 0.f;
#pragma unroll
    for (int i = 0; i < D; ++i) {
        float xi = __shfl(xv, i, 32);
        sa = fmaf(xi, Aw[i * D + j], sa);
        da = fmaf(xi, Aw[(D + i) * D + j], da);
        b0 = fmaf(xi, bases[0 * D * D + i * D + j], b0);
        b1 = fmaf(xi, bases[1 * D * D + i * D + j], b1);
        b2 = fmaf(xi, bases[2 * D * D + i * D + j], b2);
        b3 = fmaf(xi, bases[3 * D * D + i * D + j], b3);
        cu = fmaf(xi, selfw[i * D + j], cu);
    }
    uint3 u;
    u.x = f2bf(sa) | (f2bf(b0) << 16);
    u.y = f2bf(b1) | (f2bf(b2) << 16);
    u.z = f2bf(b3);
    *(uint3*)(rec + (size_t)n * RECW + j * 3) = u;
    dA[n * D + j] = da;
    nei[n * D + j] = cu;
}

// Node stage layer 1: x1 = relu(nei) (fused layer-0 finalize), then same.
__global__ void node_stage_l1(const float* __restrict__ Aw,
                              const float* __restrict__ bases,
                              const float* __restrict__ selfw,
                              unsigned* __restrict__ rec,
                              float* __restrict__ dA,
                              float* __restrict__ nei) {
    int t = blockIdx.x * blockDim.x + threadIdx.x;
    int n = t >> 5, j = t & 31;
    if (n >= N) return;
    float xv = fmaxf(nei[n * D + j], 0.f);
    float sa = 0.f, da = 0.f, cu = 0.f;
    float b0 = 0.f, b1 = 0.f, b2 = 0.f, b3 = 0.f;
#pragma unroll
    for (int i = 0; i < D; ++i) {
        float xi = __shfl(xv, i, 32);
        sa = fmaf(xi, Aw[i * D + j], sa);
        da = fmaf(xi, Aw[(D + i) * D + j], da);
        b0 = fmaf(xi, bases[0 * D * D + i * D + j], b0);
        b1 = fmaf(xi, bases[1 * D * D + i * D + j], b1);
        b2 = fmaf(xi, bases[2 * D * D + i * D + j], b2);
        b3 = fmaf(xi, bases[3 * D * D + i * D + j], b3);
        cu = fmaf(xi, selfw[i * D + j], cu);
    }
    uint3 u;
    u.x = f2bf(sa) | (f2bf(b0) << 16);
    u.y = f2bf(b1) | (f2bf(b2) << 16);
    u.z = f2bf(b3);
    *(uint3*)(rec + (size_t)n * RECW + j * 3) = u;
    dA[n * D + j] = da;
    nei[n * D + j] = cu;
}

// ---------------------------------------------------------------------------
// Edge stage: chunked walk of dst-sorted edges, register run-accumulation.
// One atomicAdd per dst-run; dA loaded once per run; tables in LDS.
__global__ __launch_bounds__(ET)
void edge_stage(const unsigned* __restrict__ rec,
                const float* __restrict__ dA,
                const float* __restrict__ attnA,
                const float* __restrict__ wcomp,
                const float* __restrict__ Bw,
                const float* __restrict__ Bb,
                const int2* __restrict__ es,
                float* __restrict__ nei) {
    __shared__ float attnL[R * 32];
    __shared__ float4 wcL[R];
    int tid = threadIdx.x;
    for (int i = tid; i < R * 32; i += ET) attnL[i] = attnA[i];
    if (tid < R) wcL[tid] = *(const float4*)(wcomp + tid * 4);
    __syncthreads();

    int j = tid & 31;
    int grp = (blockIdx.x * ET + tid) >> 5;
    float bw = Bw[j], bb = Bb[0];

    int k0 = grp * ECE;
    int k1 = k0 + ECE; if (k1 > E) k1 = E;
    int dprev = -1; float acc = 0.f, dAv = 0.f;
    for (int k = k0; k < k1; ++k) {
        int2 e = es[k];
        int s = e.x & 0xffff;
        int r = ((unsigned)e.x) >> 16;
        int d = e.y;
        if (d != dprev) {                  // group-uniform branch
            if (dprev >= 0) atomicAdd(&nei[(size_t)dprev * D + j], acc);
            acc = 0.f; dprev = d;
            dAv = dA[(size_t)d * D + j];   // once per run (~16 edges)
        }
        uint3 u = *(const uint3*)(rec + (size_t)s * RECW + j * 3);
        float h = __uint_as_float(u.x << 16) + dAv + attnL[r * 32 + j];
        h = fmaxf(h, 0.f);
        float pp = h * bw;
#pragma unroll
        for (int o = 16; o > 0; o >>= 1) pp += __shfl_xor(pp, o, 32);
        float a = 1.f / (1.f + __expf(-(pp + bb)));
        float4 wc = wcL[r];
        float m = wc.x * __uint_as_float(u.x & 0xffff0000u);
        m = fmaf(wc.y, __uint_as_float(u.y << 16), m);
        m = fmaf(wc.z, __uint_as_float(u.y & 0xffff0000u), m);
        m = fmaf(wc.w, __uint_as_float(u.z << 16), m);
        acc = fmaf(a, m, acc);
    }
    if (dprev >= 0) atomicAdd(&nei[(size_t)dprev * D + j], acc);
}

// ---------------------------------------------------------------------------
// out = relu(nei)
__global__ void finalize(const float4* __restrict__ nei, float4* __restrict__ out) {
    int t = blockIdx.x * blockDim.x + threadIdx.x;
    if (t >= N * D / 4) return;
    float4 v = nei[t];
    v.x = fmaxf(v.x, 0.f); v.y = fmaxf(v.y, 0.f);
    v.z = fmaxf(v.z, 0.f); v.w = fmaxf(v.w, 0.f);
    out[t] = v;
}

// ---------------------------------------------------------------------------
extern "C" void kernel_launch(void* const* d_in, const int* in_sizes, int n_in,
                              void* d_out, int out_size, void* d_ws, size_t ws_size,
                              hipStream_t stream) {
    const float* feat  = (const float*)d_in[0];
    const float* embed = (const float*)d_in[1];
    const float* attn  = (const float*)d_in[2];
    const int*   idx   = (const int*)d_in[3];
    const int*   src   = (const int*)d_in[4];
    const int*   dst   = (const int*)d_in[5];
    const int*   ety   = (const int*)d_in[6];
    const float* bases[2] = {(const float*)d_in[7],  (const float*)d_in[14]};
    const float* wcomp[2] = {(const float*)d_in[8],  (const float*)d_in[15]};
    const float* selfw[2] = {(const float*)d_in[9],  (const float*)d_in[16]};
    const float* Aw[2]    = {(const float*)d_in[10], (const float*)d_in[17]};
    const float* Ab[2]    = {(const float*)d_in[11], (const float*)d_in[18]};
    const float* Bw[2]    = {(const float*)d_in[12], (const float*)d_in[19]};
    const float* Bb[2]    = {(const float*)d_in[13], (const float*)d_in[20]};
    float* out = (float*)d_out;

    // --- workspace layout ---
    char* wsb = (char*)d_ws;
    unsigned* rec = (unsigned*)wsb;                       // 19.2 MB
    size_t o = ((size_t)N * RECW * 4 + 15) & ~(size_t)15;
    float* dA    = (float*)(wsb + o); o += (size_t)N * D * 4;        // 6.4 MB
    float* nei   = (float*)(wsb + o); o += (size_t)N * D * 4;        // 6.4 MB
    float* attnA = (float*)(wsb + o); o += (size_t)2 * R * D * 4;
    o = (o + 7) & ~(size_t)7;
    int2* es     = (int2*)(wsb + o); o += (size_t)E * 8;             // 6.4 MB
    int* cnt     = (int*)(wsb + o);  o += (size_t)N * 4;
    int* off     = (int*)(wsb + o);  o += (size_t)(N + 2) * 4;
    int* rank    = (int*)(wsb + o);  o += (size_t)E * 4;             // 3.2 MB
    int* bsum    = (int*)(wsb + o);  o += (size_t)(NSCB + 1) * 4;

    dim3 blk(256);
    int gx = (N * D + 255) / 256;     // 6250: 32 lanes/node
    int ge = (E + 255) / 256;         // 3125: 1 thread/edge
    int gf = (N * D / 4 + 255) / 256;

    // one-time graph sort + tiny precompute
    hipMemsetAsync(cnt, 0, (size_t)N * 4, stream);
    hist_rank_attnA<<<GEH + 5, blk, 0, stream>>>(dst, cnt, rank, attn,
                                                 Aw[0], Ab[0], Aw[1], Ab[1], attnA);
    scan_block_sums<<<NSCB, SCB, 0, stream>>>(cnt, bsum);
    scan_final<<<NSCB, SCB, 0, stream>>>(cnt, bsum, off);
    scatter_edges<<<ge, blk, 0, stream>>>(src, dst, ety, off, rank, es);

    // layer 0
    node_stage_l0<<<gx, blk, 0, stream>>>(feat, embed, idx, Aw[0], bases[0],
                                          selfw[0], rec, dA, nei);
    edge_stage<<<EG, ET, 0, stream>>>(rec, dA, attnA, wcomp[0], Bw[0], Bb[0],
                                      es, nei);
    // layer 1 (fused relu of layer-0 output)
    node_stage_l1<<<gx, blk, 0, stream>>>(Aw[1], bases[1], selfw[1], rec, dA, nei);
    edge_stage<<<EG, ET, 0, stream>>>(rec, dA, attnA + (size_t)R * D,
                                      wcomp[1], Bw[1], Bb[1], es, nei);
    finalize<<<gf, blk, 0, stream>>>((const float4*)nei, (float4*)out);
}

// Round 9
// 308.085 us; speedup vs baseline: 1.5893x; 1.1466x over previous
//
#include <hip/hip_runtime.h>
#include <math.h>

constexpr int N = 50000;
constexpr int E = 800000;
constexpr int D = 32;      // layer dim
constexpr int R = 20;      // relations
constexpr int RECW = 96;   // uints per node record: 32 lanes x 3 dwords (384 B)

// edge kernel geometry
constexpr int EG = 2048;                   // blocks
constexpr int ET = 256;                    // threads/block
constexpr int ENG = EG * (ET / 32);        // 16384 32-lane groups
constexpr int ECE = (E + ENG - 1) / ENG;   // 49 sorted edges per group

// node kernel geometry: 4 nodes per 32-lane group
constexpr int NQ = N / 4;                       // 12500 quads
constexpr int NODE_BLKS = (NQ + 7) / 8;         // 1563 blocks (8 groups/block)
constexpr int GES = (E + 255) / 256;            // 3125 scatter blocks

__device__ __forceinline__ unsigned f2bf(float f) {
    unsigned u = __float_as_uint(f);
    return (u + 0x7fffu + ((u >> 16) & 1u)) >> 16;   // RNE to bf16 bits
}

// ---------------------------------------------------------------------------
// Shared node-quad body: 4 nodes, weights loaded once per quad per k-step.
__device__ __forceinline__ void node_quad(int n0, int j, const float xin[4],
                                          const float* __restrict__ Aw,
                                          const float* __restrict__ bases,
                                          const float* __restrict__ selfw,
                                          unsigned* __restrict__ rec,
                                          float* __restrict__ dA,
                                          float* __restrict__ nei) {
    float sa[4] = {0,0,0,0}, da[4] = {0,0,0,0}, cu[4] = {0,0,0,0};
    float b0[4] = {0,0,0,0}, b1[4] = {0,0,0,0}, b2[4] = {0,0,0,0}, b3[4] = {0,0,0,0};
#pragma unroll
    for (int i = 0; i < D; ++i) {
        float wsa = Aw[i * D + j];
        float wda = Aw[(D + i) * D + j];
        float w0  = bases[0 * D * D + i * D + j];
        float w1  = bases[1 * D * D + i * D + j];
        float w2  = bases[2 * D * D + i * D + j];
        float w3  = bases[3 * D * D + i * D + j];
        float wcu = selfw[i * D + j];
#pragma unroll
        for (int u = 0; u < 4; ++u) {
            float xi = __shfl(xin[u], i, 32);
            sa[u] = fmaf(xi, wsa, sa[u]);
            da[u] = fmaf(xi, wda, da[u]);
            b0[u] = fmaf(xi, w0, b0[u]);
            b1[u] = fmaf(xi, w1, b1[u]);
            b2[u] = fmaf(xi, w2, b2[u]);
            b3[u] = fmaf(xi, w3, b3[u]);
            cu[u] = fmaf(xi, wcu, cu[u]);
        }
    }
#pragma unroll
    for (int u = 0; u < 4; ++u) {
        int n = n0 + u;
        if (n < N) {
            uint3 w;
            w.x = f2bf(sa[u]) | (f2bf(b0[u]) << 16);
            w.y = f2bf(b1[u]) | (f2bf(b2[u]) << 16);
            w.z = f2bf(b3[u]);
            *(uint3*)(rec + (size_t)n * RECW + j * 3) = w;
            dA[n * D + j]  = da[u];
            nei[n * D + j] = cu[u];
        }
    }
}

// ---------------------------------------------------------------------------
// hist+rank over edges; trailing blocks compute attnA[2][R][32].
__global__ void hist_rank_attnA(const int* __restrict__ dst,
                                int* __restrict__ cnt,
                                int* __restrict__ rank,
                                const float* __restrict__ attn,
                                const float* __restrict__ Aw0,
                                const float* __restrict__ Ab0,
                                const float* __restrict__ Aw1,
                                const float* __restrict__ Ab1,
                                float* __restrict__ attnA) {
    int b = blockIdx.x;
    if (b < GES) {
        int e = b * 256 + threadIdx.x;
        if (e < E) rank[e] = atomicAdd(&cnt[dst[e]], 1);
    } else {
        int i = (b - GES) * 256 + threadIdx.x;   // 0..1279
        if (i < 2 * R * 32) {
            int l = i / (R * 32), rem = i % (R * 32), r = rem / 32, jj = rem & 31;
            const float* Aw = l ? Aw1 : Aw0;
            const float* Ab = l ? Ab1 : Ab0;
            float acc = Ab[jj];
            for (int k = 0; k < 32; ++k)
                acc = fmaf(attn[r * 32 + k], Aw[(64 + k) * D + jj], acc);
            attnA[i] = acc;
        }
    }
}

// ---------------------------------------------------------------------------
// One-kernel exclusive scan: block b sums cnt[0..b*1024) itself, then scans
// its own 1024-chunk in LDS.  49 blocks; prefix reads come from L2.
constexpr int SCB = 1024;
constexpr int NSCB = (N + SCB - 1) / SCB;   // 49

__global__ __launch_bounds__(SCB)
void scan_all(const int* __restrict__ cnt, int* __restrict__ off) {
    __shared__ int sdata[SCB];
    int tid = threadIdx.x;
    int lim = blockIdx.x * SCB;
    int partial = 0;
    for (int i = tid; i < lim; i += SCB) partial += cnt[i];
    sdata[tid] = partial;
    __syncthreads();
    for (int s = SCB / 2; s > 0; s >>= 1) {
        if (tid < s) sdata[tid] += sdata[tid + s];
        __syncthreads();
    }
    int bbase = sdata[0];
    __syncthreads();
    int i = lim + tid;
    int v = (i < N) ? cnt[i] : 0;
    sdata[tid] = v;
    __syncthreads();
    for (int d = 1; d < SCB; d <<= 1) {
        int u = (tid >= d) ? sdata[tid - d] : 0;
        __syncthreads();
        sdata[tid] += u;
        __syncthreads();
    }
    if (i < N) {
        int excl = sdata[tid] - v + bbase;
        off[i] = excl;
        if (i == N - 1) off[N] = excl + v;   // == E
    }
}

// ---------------------------------------------------------------------------
// Fused: blocks [0,GES) scatter edges; blocks [GES, GES+NODE_BLKS) node stage l0.
__global__ __launch_bounds__(256)
void scatter_node_l0(const int* __restrict__ src,
                     const int* __restrict__ dst,
                     const int* __restrict__ ety,
                     const int* __restrict__ off,
                     const int* __restrict__ rank,
                     int2* __restrict__ es,
                     const float* __restrict__ feat,
                     const float* __restrict__ embed,
                     const int* __restrict__ idx,
                     const float* __restrict__ Aw,
                     const float* __restrict__ bases,
                     const float* __restrict__ selfw,
                     unsigned* __restrict__ rec,
                     float* __restrict__ dA,
                     float* __restrict__ nei) {
    int b = blockIdx.x;
    if (b < GES) {
        int e = b * 256 + threadIdx.x;
        if (e < E) {
            int d = dst[e];
            es[off[d] + rank[e]] = make_int2(src[e] | (ety[e] << 16), d);
        }
        return;
    }
    int qid = ((b - GES) * 256 + threadIdx.x) >> 5;
    if (qid >= NQ) return;
    int j = threadIdx.x & 31;
    int n0 = qid * 4;
    float xin[4];
#pragma unroll
    for (int u = 0; u < 4; ++u) {
        int n = n0 + u;
        xin[u] = (n < N)
            ? ((j < 16) ? feat[n * 16 + j] : embed[idx[n] * 16 + (j - 16)])
            : 0.f;
    }
    node_quad(n0, j, xin, Aw, bases, selfw, rec, dA, nei);
}

// ---------------------------------------------------------------------------
// Node stage layer 1: x1 = relu(nei) (fused layer-0 finalize), then quad body.
__global__ __launch_bounds__(256)
void node_stage_l1(const float* __restrict__ Aw,
                   const float* __restrict__ bases,
                   const float* __restrict__ selfw,
                   unsigned* __restrict__ rec,
                   float* __restrict__ dA,
                   float* __restrict__ nei) {
    int qid = (blockIdx.x * 256 + threadIdx.x) >> 5;
    if (qid >= NQ) return;
    int j = threadIdx.x & 31;
    int n0 = qid * 4;
    float xin[4];
#pragma unroll
    for (int u = 0; u < 4; ++u) {
        int n = n0 + u;
        xin[u] = (n < N) ? fmaxf(nei[n * D + j], 0.f) : 0.f;
    }
    node_quad(n0, j, xin, Aw, bases, selfw, rec, dA, nei);
}

// ---------------------------------------------------------------------------
// Edge stage: chunked walk of dst-sorted edges, register run-accumulation.
__global__ __launch_bounds__(ET)
void edge_stage(const unsigned* __restrict__ rec,
                const float* __restrict__ dA,
                const float* __restrict__ attnA,
                const float* __restrict__ wcomp,
                const float* __restrict__ Bw,
                const float* __restrict__ Bb,
                const int2* __restrict__ es,
                float* __restrict__ nei) {
    __shared__ float attnL[R * 32];
    __shared__ float4 wcL[R];
    int tid = threadIdx.x;
    for (int i = tid; i < R * 32; i += ET) attnL[i] = attnA[i];
    if (tid < R) wcL[tid] = *(const float4*)(wcomp + tid * 4);
    __syncthreads();

    int j = tid & 31;
    int grp = (blockIdx.x * ET + tid) >> 5;
    float bw = Bw[j], bb = Bb[0];

    int k0 = grp * ECE;
    int k1 = k0 + ECE; if (k1 > E) k1 = E;
    int dprev = -1; float acc = 0.f, dAv = 0.f;
    for (int k = k0; k < k1; ++k) {
        int2 e = es[k];
        int s = e.x & 0xffff;
        int r = ((unsigned)e.x) >> 16;
        int d = e.y;
        if (d != dprev) {                  // group-uniform branch
            if (dprev >= 0) atomicAdd(&nei[(size_t)dprev * D + j], acc);
            acc = 0.f; dprev = d;
            dAv = dA[(size_t)d * D + j];   // once per run (~16 edges)
        }
        uint3 u = *(const uint3*)(rec + (size_t)s * RECW + j * 3);
        float h = __uint_as_float(u.x << 16) + dAv + attnL[r * 32 + j];
        h = fmaxf(h, 0.f);
        float pp = h * bw;
#pragma unroll
        for (int o = 16; o > 0; o >>= 1) pp += __shfl_xor(pp, o, 32);
        float a = 1.f / (1.f + __expf(-(pp + bb)));
        float4 wc = wcL[r];
        float m = wc.x * __uint_as_float(u.x & 0xffff0000u);
        m = fmaf(wc.y, __uint_as_float(u.y << 16), m);
        m = fmaf(wc.z, __uint_as_float(u.y & 0xffff0000u), m);
        m = fmaf(wc.w, __uint_as_float(u.z << 16), m);
        acc = fmaf(a, m, acc);
    }
    if (dprev >= 0) atomicAdd(&nei[(size_t)dprev * D + j], acc);
}

// ---------------------------------------------------------------------------
// out = relu(nei)
__global__ void finalize(const float4* __restrict__ nei, float4* __restrict__ out) {
    int t = blockIdx.x * blockDim.x + threadIdx.x;
    if (t >= N * D / 4) return;
    float4 v = nei[t];
    v.x = fmaxf(v.x, 0.f); v.y = fmaxf(v.y, 0.f);
    v.z = fmaxf(v.z, 0.f); v.w = fmaxf(v.w, 0.f);
    out[t] = v;
}

// ---------------------------------------------------------------------------
extern "C" void kernel_launch(void* const* d_in, const int* in_sizes, int n_in,
                              void* d_out, int out_size, void* d_ws, size_t ws_size,
                              hipStream_t stream) {
    const float* feat  = (const float*)d_in[0];
    const float* embed = (const float*)d_in[1];
    const float* attn  = (const float*)d_in[2];
    const int*   idx   = (const int*)d_in[3];
    const int*   src   = (const int*)d_in[4];
    const int*   dst   = (const int*)d_in[5];
    const int*   ety   = (const int*)d_in[6];
    const float* bases[2] = {(const float*)d_in[7],  (const float*)d_in[14]};
    const float* wcomp[2] = {(const float*)d_in[8],  (const float*)d_in[15]};
    const float* selfw[2] = {(const float*)d_in[9],  (const float*)d_in[16]};
    const float* Aw[2]    = {(const float*)d_in[10], (const float*)d_in[17]};
    const float* Ab[2]    = {(const float*)d_in[11], (const float*)d_in[18]};
    const float* Bw[2]    = {(const float*)d_in[12], (const float*)d_in[19]};
    const float* Bb[2]    = {(const float*)d_in[13], (const float*)d_in[20]};
    float* out = (float*)d_out;

    // --- workspace layout ---
    char* wsb = (char*)d_ws;
    unsigned* rec = (unsigned*)wsb;                       // 19.2 MB
    size_t o = ((size_t)N * RECW * 4 + 15) & ~(size_t)15;
    float* dA    = (float*)(wsb + o); o += (size_t)N * D * 4;        // 6.4 MB
    float* nei   = (float*)(wsb + o); o += (size_t)N * D * 4;        // 6.4 MB
    float* attnA = (float*)(wsb + o); o += (size_t)2 * R * D * 4;
    o = (o + 7) & ~(size_t)7;
    int2* es     = (int2*)(wsb + o); o += (size_t)E * 8;             // 6.4 MB
    int* cnt     = (int*)(wsb + o);  o += (size_t)N * 4;
    int* off     = (int*)(wsb + o);  o += (size_t)(N + 2) * 4;
    int* rank    = (int*)(wsb + o);  o += (size_t)E * 4;             // 3.2 MB

    dim3 blk(256);
    int gf = (N * D / 4 + 255) / 256;

    // sort + tiny precompute
    hipMemsetAsync(cnt, 0, (size_t)N * 4, stream);
    hist_rank_attnA<<<GES + 5, blk, 0, stream>>>(dst, cnt, rank, attn,
                                                 Aw[0], Ab[0], Aw[1], Ab[1], attnA);
    scan_all<<<NSCB, SCB, 0, stream>>>(cnt, off);

    // fused scatter + layer-0 node stage
    scatter_node_l0<<<GES + NODE_BLKS, blk, 0, stream>>>(
        src, dst, ety, off, rank, es,
        feat, embed, idx, Aw[0], bases[0], selfw[0], rec, dA, nei);
    edge_stage<<<EG, ET, 0, stream>>>(rec, dA, attnA, wcomp[0], Bw[0], Bb[0],
                                      es, nei);
    // layer 1
    node_stage_l1<<<NODE_BLKS, blk, 0, stream>>>(Aw[1], bases[1], selfw[1],
                                                 rec, dA, nei);
    edge_stage<<<EG, ET, 0, stream>>>(rec, dA, attnA + (size_t)R * D,
                                      wcomp[1], Bw[1], Bb[1], es, nei);
    finalize<<<gf, blk, 0, stream>>>((const float4*)nei, (float4*)out);
}